// Round 14
// baseline (129.045 us; speedup 1.0000x reference)
//
#include <hip/hip_runtime.h>

// KMeans soft-assignment via bf16 hi/lo split MFMA (3 passes), fused softmax.
// logits = (2*x.c - ||c||^2)/T, T=0.1; ||x||^2 cancels in softmax.
// R14: R10 base (DMA double-buffer, zero staging regs) + squarer wave tile:
// wave = 64 rows x 128 cols (mt=4, nt=8) -> each B-fragment pair feeds 12
// MFMAs (was 6), halving per-CU LDS fragment traffic in the MFMA phase.
// x: [32768,256] f32, c: [512,256] f32, out: [32768,512] f32
#define NROWS 32768
#define KC 512
#define DDIM 256
#define BM 128
#define BK 32
#define KCH (DDIM / BK)        // 8 k-chunks
#define CHUNK_USH (KC * BK)    // 16384 ushorts = 32 KB per chunk table

typedef __attribute__((ext_vector_type(8))) short bf16x8;
typedef __attribute__((ext_vector_type(4))) float f32x4;

union U8 { unsigned short u[8]; bf16x8 v; };

__device__ __forceinline__ unsigned short f2bf(float f) {   // RNE f32->bf16
    union { float f; unsigned int u; } a; a.f = f;
    unsigned int r = a.u + 0x7fffu + ((a.u >> 16) & 1u);
    return (unsigned short)(r >> 16);
}
__device__ __forceinline__ float bf2f(unsigned short h) {
    union { unsigned int u; float f; } a; a.u = ((unsigned int)h) << 16;
    return a.f;
}
// async global->LDS, 16B/lane; LDS dst = wave-uniform base + lane*16
__device__ __forceinline__ void ld16(const void* g, void* l) {
    __builtin_amdgcn_global_load_lds(
        (const __attribute__((address_space(1))) unsigned int*)g,
        (__attribute__((address_space(3))) unsigned int*)l, 16, 0, 0);
}

// ---- prep: c -> chunk-major, LDS-swizzle-baked bf16 hi/lo + csq10 (R10, verified) ----
// octet (col n, quad q) at chunk offset (n*4 + (q ^ ((n>>1)&3)))*8 ushorts
__global__ __launch_bounds__(64) void prep_c(const float* __restrict__ c,
                                             unsigned short* __restrict__ bhi,
                                             unsigned short* __restrict__ blo,
                                             float* __restrict__ csq10) {
    const int n = blockIdx.x, lane = threadIdx.x;
    const int d0 = lane * 4;
    float4 v = ((const float4*)(c + (size_t)n * DDIM))[lane];
    float vv[4] = {v.x, v.y, v.z, v.w};
    unsigned short hh[4], ll[4];
    float ssq = 0.f;
    #pragma unroll
    for (int i = 0; i < 4; ++i) {
        ssq += vv[i] * vv[i];
        hh[i] = f2bf(vv[i]);
        ll[i] = f2bf(vv[i] - bf2f(hh[i]));
    }
    #pragma unroll
    for (int off = 32; off; off >>= 1) ssq += __shfl_xor(ssq, off);
    if (lane == 0) csq10[n] = 10.f * ssq;
    const int ks = d0 >> 5;
    const int q  = (d0 >> 3) & 3;
    const int s  = q ^ ((n >> 1) & 3);
    const size_t dst = (size_t)ks * CHUNK_USH + (n * 4 + s) * 8 + (d0 & 7);
    *(ushort4*)(bhi + dst) = make_ushort4(hh[0], hh[1], hh[2], hh[3]);
    *(ushort4*)(blo + dst) = make_ushort4(ll[0], ll[1], ll[2], ll[3]);
}

// ---- main: 256 blocks x 512 threads (8 waves = 2 M-halves x 4 N-quarters) ----
// wave (wm,wn): rows wm*64 + mt*16 (mt=0..3), cols wn*128 + t*16 (t=0..7)
union SmemU {
    struct { unsigned short Bh[2][CHUNK_USH], Bl[2][CHUNK_USH]; } k;  // 128 KB
    float lbuf[32 * 516];                                             // 66 KB overlay
};

__global__ __launch_bounds__(512, 2) void kmeans_mfma(
    const float* __restrict__ x, const unsigned short* __restrict__ bhi,
    const unsigned short* __restrict__ blo, const float* __restrict__ csq10,
    float* __restrict__ out) {
    __shared__ __align__(16) SmemU sm;
    __shared__ float  red0[4][BM], red1[4][BM];   // 4 KB
    __shared__ float2 MI[BM];                     // 1 KB

    const int tid  = threadIdx.x;
    const int w    = tid >> 6, lane = tid & 63;
    const int wm   = w >> 2, wn = w & 3;
    const int cc   = lane & 15, q = lane >> 4;
    const int row0 = blockIdx.x * BM;

    f32x4 acc[4][8];
    #pragma unroll
    for (int mt = 0; mt < 4; ++mt)
        #pragma unroll
        for (int t = 0; t < 8; ++t) acc[mt][t] = (f32x4){0.f, 0.f, 0.f, 0.f};

    // A: lane owns rows (row0 + wm*64 + mt*16 + cc), k-octet q*8 per chunk
    const float* xA[4];
    #pragma unroll
    for (int mt = 0; mt < 4; ++mt)
        xA[mt] = x + (size_t)(row0 + wm * 64 + mt * 16 + cc) * DDIM + q * 8;
    // B fragment offset within staged chunk
    const int sF = q ^ ((cc >> 1) & 3);
    const int bF = (4 * cc + sF) * 8;       // + (wn*8+t)*512
    const int dmaOff = (w * 4) * 512;       // wave's 4 x 1KB DMA segments

    // ---- prologue: DMA chunk 0 -> buf 0; A(0) raw ----
    #pragma unroll
    for (int j = 0; j < 4; ++j) {
        const int o = dmaOff + j * 512;
        ld16(bhi + o + lane * 8, &sm.k.Bh[0][o]);
        ld16(blo + o + lane * 8, &sm.k.Bl[0][o]);
    }
    float4 a[4][2];
    #pragma unroll
    for (int mt = 0; mt < 4; ++mt) {
        a[mt][0] = *(const float4*)(xA[mt]);
        a[mt][1] = *(const float4*)(xA[mt] + 4);
    }
    __syncthreads();   // DMA for buf0 drained

    for (int ks = 0; ks < KCH; ++ks) {
        const int pp = ks & 1;
        float4 n[4][2];
        if (ks < KCH - 1) {
            // issue DMA for next chunk into other buffer (lands under MFMA)
            const size_t cb = (size_t)(ks + 1) * CHUNK_USH;
            #pragma unroll
            for (int j = 0; j < 4; ++j) {
                const int o = dmaOff + j * 512;
                ld16(bhi + cb + o + lane * 8, &sm.k.Bh[1 - pp][o]);
                ld16(blo + cb + o + lane * 8, &sm.k.Bl[1 - pp][o]);
            }
            const int kn = (ks + 1) * BK;
            #pragma unroll
            for (int mt = 0; mt < 4; ++mt) {
                n[mt][0] = *(const float4*)(xA[mt] + kn);
                n[mt][1] = *(const float4*)(xA[mt] + kn + 4);
            }
        }
        // convert current A to hi/lo fragments
        bf16x8 ah[4], al[4];
        #pragma unroll
        for (int mt = 0; mt < 4; ++mt) {
            float v8[8] = {a[mt][0].x, a[mt][0].y, a[mt][0].z, a[mt][0].w,
                           a[mt][1].x, a[mt][1].y, a[mt][1].z, a[mt][1].w};
            U8 H, L;
            #pragma unroll
            for (int i = 0; i < 8; ++i) {
                H.u[i] = f2bf(v8[i]);
                L.u[i] = f2bf(v8[i] - bf2f(H.u[i]));
            }
            ah[mt] = H.v; al[mt] = L.v;
        }
        // MFMA phase: each bh/bl pair feeds 12 MFMAs (4 mt x 3 passes)
        #pragma unroll
        for (int t = 0; t < 8; ++t) {
            const int bo = (wn * 8 + t) * 512 + bF;
            bf16x8 bh = *(const bf16x8*)&sm.k.Bh[pp][bo];
            bf16x8 bl = *(const bf16x8*)&sm.k.Bl[pp][bo];
            #pragma unroll
            for (int mt = 0; mt < 4; ++mt) {
                acc[mt][t] = __builtin_amdgcn_mfma_f32_16x16x32_bf16(ah[mt], bh, acc[mt][t], 0, 0, 0);
                acc[mt][t] = __builtin_amdgcn_mfma_f32_16x16x32_bf16(ah[mt], bl, acc[mt][t], 0, 0, 0);
                acc[mt][t] = __builtin_amdgcn_mfma_f32_16x16x32_bf16(al[mt], bh, acc[mt][t], 0, 0, 0);
            }
        }
        #pragma unroll
        for (int mt = 0; mt < 4; ++mt) { a[mt][0] = n[mt][0]; a[mt][1] = n[mt][1]; }
        __syncthreads();   // next-chunk DMA drained; all waves done with buf pp
    }

    // ---- softmax stats; C/D: col = wn*128 + t*16 + cc, row = wm*64+mt*16+q*4+g
    float csqv[8];
    #pragma unroll
    for (int t = 0; t < 8; ++t) csqv[t] = csq10[wn * 128 + t * 16 + cc];

    #pragma unroll
    for (int mt = 0; mt < 4; ++mt)
        #pragma unroll
        for (int g = 0; g < 4; ++g) {
            float pm = -1e30f;
            #pragma unroll
            for (int t = 0; t < 8; ++t) pm = fmaxf(pm, 20.f * acc[mt][t][g] - csqv[t]);
            #pragma unroll
            for (int off = 1; off < 16; off <<= 1) pm = fmaxf(pm, __shfl_xor(pm, off));
            if (cc == 0) red0[wn][wm * 64 + mt * 16 + q * 4 + g] = pm;
        }
    __syncthreads();
    float M[4][4];
    #pragma unroll
    for (int mt = 0; mt < 4; ++mt)
        #pragma unroll
        for (int g = 0; g < 4; ++g) {
            const int row = wm * 64 + mt * 16 + q * 4 + g;
            float Mf = fmaxf(fmaxf(red0[0][row], red0[1][row]),
                             fmaxf(red0[2][row], red0[3][row]));
            M[mt][g] = Mf;
            float ps = 0.f;
            #pragma unroll
            for (int t = 0; t < 8; ++t) ps += __expf(20.f * acc[mt][t][g] - csqv[t] - Mf);
            #pragma unroll
            for (int off = 1; off < 16; off <<= 1) ps += __shfl_xor(ps, off);
            if (cc == 0) red1[wn][row] = ps;
        }
    __syncthreads();
    if (tid < BM) {
        const float Mf = fmaxf(fmaxf(red0[0][tid], red0[1][tid]),
                               fmaxf(red0[2][tid], red0[3][tid]));
        const float Sf = red1[0][tid] + red1[1][tid] + red1[2][tid] + red1[3][tid];
        MI[tid] = make_float2(Mf, 1.f / Sf);
    }
    __syncthreads();

    // ---- transpose epilogue: 4 passes of 32 rows through lbuf ----
    #pragma unroll
    for (int p = 0; p < 4; ++p) {
        if (wm == (p >> 1)) {
            #pragma unroll
            for (int mi = 0; mi < 2; ++mi) {
                const int mt = (p & 1) * 2 + mi;
                #pragma unroll
                for (int g = 0; g < 4; ++g) {
                    const int    lr  = mi * 16 + q * 4 + g;      // 0..31
                    const float2 mi2 = MI[p * 32 + lr];
                    #pragma unroll
                    for (int t = 0; t < 8; ++t)
                        sm.lbuf[lr * 516 + wn * 128 + t * 16 + cc] =
                            __expf(20.f * acc[mt][t][g] - csqv[t] - mi2.x) * mi2.y;
                }
            }
        }
        __syncthreads();
        #pragma unroll
        for (int j = 0; j < 8; ++j) {
            const int f    = j * 512 + tid;     // 0..4095 float4 slots
            const int lrow = f >> 7;            // 0..31
            const int c4   = f & 127;
            float4    v    = *(const float4*)&sm.lbuf[lrow * 516 + c4 * 4];
            *(float4*)(out + (size_t)(row0 + p * 32 + lrow) * KC + c4 * 4) = v;
        }
        __syncthreads();
    }
}

extern "C" void kernel_launch(void* const* d_in, const int* in_sizes, int n_in,
                              void* d_out, int out_size, void* d_ws, size_t ws_size,
                              hipStream_t stream) {
    const float* x   = (const float*)d_in[0];
    const float* c   = (const float*)d_in[1];
    float*       out = (float*)d_out;

    unsigned short* bhi   = (unsigned short*)d_ws;                 // 256 KB
    unsigned short* blo   = bhi + (size_t)KCH * CHUNK_USH;         // 256 KB
    float*          csq10 = (float*)(blo + (size_t)KCH * CHUNK_USH);  // 2 KB

    prep_c<<<KC, 64, 0, stream>>>(c, bhi, blo, csq10);
    kmeans_mfma<<<NROWS / BM, 512, 0, stream>>>(x, bhi, blo, csq10, out);
}

// Round 15
// 122.785 us; speedup vs baseline: 1.0510x; 1.0510x over previous
//
#include <hip/hip_runtime.h>

// KMeans soft-assignment via bf16 hi/lo split MFMA (3 passes), fused softmax.
// logits = (2*x.c - ||c||^2)/T, T=0.1; ||x||^2 cancels in softmax.
// R15: operand-BW fix. Wave = 128 rows x 64 cols (mt=8, nt=4): B-fragment
// traffic per MFMA drops 4x vs R10 -> K-loop becomes MFMA-pipe-bound.
// A staged per-chunk in LDS (pre-converted hi/lo, 80B row stride = aligned,
// 2-way banks); B via R10's verified zero-register DMA double-buffer.
// x: [32768,256] f32, c: [512,256] f32, out: [32768,512] f32
#define NROWS 32768
#define KC 512
#define DDIM 256
#define BM 128
#define BK 32
#define KCH (DDIM / BK)        // 8 k-chunks
#define CHUNK_USH (KC * BK)    // 16384 ushorts = 32 KB per chunk table
#define ASTR 40                // A-LDS row stride in ushorts (80 B: 16B-aligned, 2-way banks)

typedef __attribute__((ext_vector_type(8))) short bf16x8;
typedef __attribute__((ext_vector_type(4))) float f32x4;

union U8 { unsigned short u[8]; bf16x8 v; };

__device__ __forceinline__ unsigned short f2bf(float f) {   // RNE f32->bf16
    union { float f; unsigned int u; } a; a.f = f;
    unsigned int r = a.u + 0x7fffu + ((a.u >> 16) & 1u);
    return (unsigned short)(r >> 16);
}
__device__ __forceinline__ float bf2f(unsigned short h) {
    union { unsigned int u; float f; } a; a.u = ((unsigned int)h) << 16;
    return a.f;
}
// async global->LDS, 16B/lane; LDS dst = wave-uniform base + lane*16
__device__ __forceinline__ void ld16(const void* g, void* l) {
    __builtin_amdgcn_global_load_lds(
        (const __attribute__((address_space(1))) unsigned int*)g,
        (__attribute__((address_space(3))) unsigned int*)l, 16, 0, 0);
}

// ---- prep: c -> chunk-major, LDS-swizzle-baked bf16 hi/lo + csq10 (R10, verified) ----
// octet (col n, quad q) at chunk offset (n*4 + (q ^ ((n>>1)&3)))*8 ushorts
__global__ __launch_bounds__(64) void prep_c(const float* __restrict__ c,
                                             unsigned short* __restrict__ bhi,
                                             unsigned short* __restrict__ blo,
                                             float* __restrict__ csq10) {
    const int n = blockIdx.x, lane = threadIdx.x;
    const int d0 = lane * 4;
    float4 v = ((const float4*)(c + (size_t)n * DDIM))[lane];
    float vv[4] = {v.x, v.y, v.z, v.w};
    unsigned short hh[4], ll[4];
    float ssq = 0.f;
    #pragma unroll
    for (int i = 0; i < 4; ++i) {
        ssq += vv[i] * vv[i];
        hh[i] = f2bf(vv[i]);
        ll[i] = f2bf(vv[i] - bf2f(hh[i]));
    }
    #pragma unroll
    for (int off = 32; off; off >>= 1) ssq += __shfl_xor(ssq, off);
    if (lane == 0) csq10[n] = 10.f * ssq;
    const int ks = d0 >> 5;
    const int q  = (d0 >> 3) & 3;
    const int s  = q ^ ((n >> 1) & 3);
    const size_t dst = (size_t)ks * CHUNK_USH + (n * 4 + s) * 8 + (d0 & 7);
    *(ushort4*)(bhi + dst) = make_ushort4(hh[0], hh[1], hh[2], hh[3]);
    *(ushort4*)(blo + dst) = make_ushort4(ll[0], ll[1], ll[2], ll[3]);
}

// ---- main: 256 blocks x 512 threads (8 waves; wave wn = all 128 rows x cols wn*64..+63) ----
union SmemU {
    struct { unsigned short Bh[2][CHUNK_USH], Bl[2][CHUNK_USH]; } k;  // 128 KB
    struct {
        float  lbuf[32 * 516];          // 66 KB
        float  red0[8][BM];             // 4 KB
        float  red1[8][BM];             // 4 KB
        float2 MI[BM];                  // 1 KB
    } e;
};

__global__ __launch_bounds__(512, 2) void kmeans_mfma(
    const float* __restrict__ x, const unsigned short* __restrict__ bhi,
    const unsigned short* __restrict__ blo, const float* __restrict__ csq10,
    float* __restrict__ out) {
    __shared__ __align__(16) SmemU sm;
    __shared__ __align__(16) unsigned short Ah[BM * ASTR], Al[BM * ASTR];  // 10 KB each

    const int tid  = threadIdx.x;
    const int wn   = tid >> 6, lane = tid & 63;
    const int cc   = lane & 15, q = lane >> 4;
    const int row0 = blockIdx.x * BM;

    f32x4 acc[8][4];
    #pragma unroll
    for (int mt = 0; mt < 8; ++mt)
        #pragma unroll
        for (int t = 0; t < 4; ++t) acc[mt][t] = (f32x4){0.f, 0.f, 0.f, 0.f};

    // A staging: thread -> (row tid>>2, octet tid&3)
    const int       sRow = tid >> 2, sOct = tid & 3;
    const float*    xg   = x + (size_t)(row0 + sRow) * DDIM + sOct * 8;
    unsigned short* aHiW = &Ah[sRow * ASTR + sOct * 8];
    unsigned short* aLoW = &Al[sRow * ASTR + sOct * 8];

    // fragment read offsets
    const int sF = q ^ ((cc >> 1) & 3);
    const int bF = (4 * cc + sF) * 8;       // + (wn*4+t)*512 within chunk
    const int dmaOff = (wn * 4) * 512;      // wave's 4 x 1KB DMA segments

    // ---- prologue: DMA B(0) -> buf 0; stage A(0) ----
    #pragma unroll
    for (int j = 0; j < 4; ++j) {
        const int o = dmaOff + j * 512;
        ld16(bhi + o + lane * 8, &sm.k.Bh[0][o]);
        ld16(blo + o + lane * 8, &sm.k.Bl[0][o]);
    }
    {
        float4 p0 = *(const float4*)xg;
        float4 p1 = *(const float4*)(xg + 4);
        float v8[8] = {p0.x, p0.y, p0.z, p0.w, p1.x, p1.y, p1.z, p1.w};
        U8 H, L;
        #pragma unroll
        for (int i = 0; i < 8; ++i) {
            H.u[i] = f2bf(v8[i]);
            L.u[i] = f2bf(v8[i] - bf2f(H.u[i]));
        }
        *(bf16x8*)aHiW = H.v;
        *(bf16x8*)aLoW = L.v;
    }
    __syncthreads();   // DMA(0) drained, A(0) visible

    for (int ks = 0; ks < KCH; ++ks) {
        const int pp = ks & 1;
        float4 p0, p1;
        if (ks < KCH - 1) {
            // DMA B(ks+1) into other buffer (lands under MFMA phase)
            const size_t cb = (size_t)(ks + 1) * CHUNK_USH;
            #pragma unroll
            for (int j = 0; j < 4; ++j) {
                const int o = dmaOff + j * 512;
                ld16(bhi + cb + o + lane * 8, &sm.k.Bh[1 - pp][o]);
                ld16(blo + cb + o + lane * 8, &sm.k.Bl[1 - pp][o]);
            }
            // prefetch x(ks+1) raw
            p0 = *(const float4*)(xg + (ks + 1) * BK);
            p1 = *(const float4*)(xg + (ks + 1) * BK + 4);
        }
        // ---- MFMA phase: hold 4 B tile-pairs, stream A over mt ----
        bf16x8 bh[4], bl[4];
        #pragma unroll
        for (int t = 0; t < 4; ++t) {
            const int bo = (wn * 4 + t) * 512 + bF;
            bh[t] = *(const bf16x8*)&sm.k.Bh[pp][bo];
            bl[t] = *(const bf16x8*)&sm.k.Bl[pp][bo];
        }
        #pragma unroll
        for (int mt = 0; mt < 8; ++mt) {
            const int ao = (mt * 16 + cc) * ASTR + q * 8;
            bf16x8 ah = *(const bf16x8*)&Ah[ao];
            bf16x8 al = *(const bf16x8*)&Al[ao];
            #pragma unroll
            for (int t = 0; t < 4; ++t) {
                acc[mt][t] = __builtin_amdgcn_mfma_f32_16x16x32_bf16(ah, bh[t], acc[mt][t], 0, 0, 0);
                acc[mt][t] = __builtin_amdgcn_mfma_f32_16x16x32_bf16(ah, bl[t], acc[mt][t], 0, 0, 0);
                acc[mt][t] = __builtin_amdgcn_mfma_f32_16x16x32_bf16(al, bh[t], acc[mt][t], 0, 0, 0);
            }
        }
        __syncthreads();   // MFMA(ks) done; DMA(ks+1) drained; x-prefetch complete
        if (ks < KCH - 1) {
            float v8[8] = {p0.x, p0.y, p0.z, p0.w, p1.x, p1.y, p1.z, p1.w};
            U8 H, L;
            #pragma unroll
            for (int i = 0; i < 8; ++i) {
                H.u[i] = f2bf(v8[i]);
                L.u[i] = f2bf(v8[i] - bf2f(H.u[i]));
            }
            *(bf16x8*)aHiW = H.v;
            *(bf16x8*)aLoW = L.v;
        }
        __syncthreads();   // A(ks+1) visible (lgkm-only barrier)
    }

    // ---- softmax stats; C/D: col = wn*64 + t*16 + cc, row = mt*16 + q*4 + g
    float csqv[4];
    #pragma unroll
    for (int t = 0; t < 4; ++t) csqv[t] = csq10[wn * 64 + t * 16 + cc];

    #pragma unroll
    for (int mt = 0; mt < 8; ++mt)
        #pragma unroll
        for (int g = 0; g < 4; ++g) {
            float pm = -1e30f;
            #pragma unroll
            for (int t = 0; t < 4; ++t) pm = fmaxf(pm, 20.f * acc[mt][t][g] - csqv[t]);
            #pragma unroll
            for (int off = 1; off < 16; off <<= 1) pm = fmaxf(pm, __shfl_xor(pm, off));
            if (cc == 0) sm.e.red0[wn][mt * 16 + q * 4 + g] = pm;
        }
    __syncthreads();
    if (tid < BM) {
        float m = -1e30f;
        #pragma unroll
        for (int ww = 0; ww < 8; ++ww) m = fmaxf(m, sm.e.red0[ww][tid]);
        sm.e.MI[tid].x = m;
    }
    __syncthreads();
    #pragma unroll
    for (int mt = 0; mt < 8; ++mt)
        #pragma unroll
        for (int g = 0; g < 4; ++g) {
            const int   row = mt * 16 + q * 4 + g;
            const float Mf  = sm.e.MI[row].x;
            float ps = 0.f;
            #pragma unroll
            for (int t = 0; t < 4; ++t) ps += __expf(20.f * acc[mt][t][g] - csqv[t] - Mf);
            #pragma unroll
            for (int off = 1; off < 16; off <<= 1) ps += __shfl_xor(ps, off);
            if (cc == 0) sm.e.red1[wn][row] = ps;
        }
    __syncthreads();
    if (tid < BM) {
        float s = 0.f;
        #pragma unroll
        for (int ww = 0; ww < 8; ++ww) s += sm.e.red1[ww][tid];
        sm.e.MI[tid].y = 1.f / s;
    }
    __syncthreads();

    // ---- transpose epilogue: 4 passes of 32 rows (mt = 2p, 2p+1) ----
    #pragma unroll
    for (int p = 0; p < 4; ++p) {
        #pragma unroll
        for (int mi = 0; mi < 2; ++mi) {
            const int mt = p * 2 + mi;
            #pragma unroll
            for (int g = 0; g < 4; ++g) {
                const int    lr = mi * 16 + q * 4 + g;          // 0..31
                const float2 mv = sm.e.MI[p * 32 + lr];
                #pragma unroll
                for (int t = 0; t < 4; ++t)
                    sm.e.lbuf[lr * 516 + wn * 64 + t * 16 + cc] =
                        __expf(20.f * acc[mt][t][g] - csqv[t] - mv.x) * mv.y;
            }
        }
        __syncthreads();
        #pragma unroll
        for (int j = 0; j < 8; ++j) {
            const int f    = j * 512 + tid;     // 0..4095 float4 slots
            const int lrow = f >> 7;            // 0..31
            const int c4   = f & 127;
            float4    v    = *(const float4*)&sm.e.lbuf[lrow * 516 + c4 * 4];
            *(float4*)(out + (size_t)(row0 + p * 32 + lrow) * KC + c4 * 4) = v;
        }
        __syncthreads();
    }
}

extern "C" void kernel_launch(void* const* d_in, const int* in_sizes, int n_in,
                              void* d_out, int out_size, void* d_ws, size_t ws_size,
                              hipStream_t stream) {
    const float* x   = (const float*)d_in[0];
    const float* c   = (const float*)d_in[1];
    float*       out = (float*)d_out;

    unsigned short* bhi   = (unsigned short*)d_ws;                 // 256 KB
    unsigned short* blo   = bhi + (size_t)KCH * CHUNK_USH;         // 256 KB
    float*          csq10 = (float*)(blo + (size_t)KCH * CHUNK_USH);  // 2 KB

    prep_c<<<KC, 64, 0, stream>>>(c, bhi, blo, csq10);
    kmeans_mfma<<<NROWS / BM, 512, 0, stream>>>(x, bhi, blo, csq10, out);
}